// Round 8
// baseline (281.606 us; speedup 1.0000x reference)
//
#include <hip/hip_runtime.h>
#include <hip/hip_bf16.h>

// RGCN layer: out = relu(h@W0 + segment_sum(norm * h[src] @ W[rel], dst))
// R16 fused v9 (resubmit — R7 bench was an infra failure, no counters).
// R6 post-mortem: BN=16 raised occupancy 54->74% but dur 72->81us (Bt L2
// traffic doubled; MFMA-per-Bt-read halved). Occupancy is NOT the lever at
// >=54%: bound by per-wave VALU + memory service. Phase-1 accum wastes 80%
// of its FMA (acc[5] zero-masked, 20 FMA/edge-lane for 4 useful).
// v9 = v7 structure (BN=32, 48KB, proven 72.4us) + phase-1 VALU cut ~2x:
//  (a) 5-arm branch on r (uniform per 32-lane half -> 1-2 arms execute via
//      scalar-pipe exec masking; static acc[r] indices, no scratch);
//  (b) float2 packed accum via __builtin_elementwise_fma -> v_pk_fma_f32:
//      2 pk-FMA/edge vs 20 scalar FMA. acc stays 20 VGPRs.
// Tripwires: VALUBusy ~38-43 + dur ~60-66 = VALU-coupled confirmed;
// dur flat ~72 = memory-latency floor -> pivot to gather restructure/prep.
// WRITE_SIZE >>60MB = spill -> revert.

#define NN   100000
#define NE   600000
#define FEAT 128
#define RNUM 5
#define CAP  32    // edge bucket capacity; P(deg>=32)~1e-12 per node (passed R7)
#define KC   24    // k-chunks of 32 (5*128 rel + 128 identity = 768)

#define SCAT_B 2344            // ceil(NE/256)
#define PREP_T (NN * 32 + FEAT * KC * 32)
#define PREP_B ((PREP_T + 255) / 256)

typedef __attribute__((ext_vector_type(8))) short short8;
typedef __attribute__((ext_vector_type(4))) float float4v;
typedef __attribute__((ext_vector_type(2))) float float2v;

static __device__ __forceinline__ unsigned short f2bf(float x) {
  union { float f; unsigned u; } v; v.f = x;
  unsigned r = v.u + 0x7FFFu + ((v.u >> 16) & 1u);  // RNE
  return (unsigned short)(r >> 16);
}

// ---- merged: edge->bucket scatter + (h -> bf16 hb, frag-linear bf16 Bt) -----
// Bt granule g = (c*8+n0)*64+ln (16B, j=0..7) holds B[k][o] for
// o = n0*16+(ln&15), k = c*32+((ln>>4)<<3)+j  (c = 0..23).
__global__ void k_prep(const int* __restrict__ src, const int* __restrict__ dst,
                       const int* __restrict__ eid, const float* __restrict__ norm,
                       const float* __restrict__ h, const float* __restrict__ weight,
                       const float* __restrict__ W0, int* __restrict__ cnt,
                       int2* __restrict__ s_edge, unsigned short* __restrict__ hb,
                       unsigned short* __restrict__ Bt) {
  int bid = blockIdx.x;
  if (bid < SCAT_B) {
    int e = bid * 256 + threadIdx.x;
    if (e < NE) {
      int d = dst[e];
      int p = atomicAdd(&cnt[d], 1);
      if (p < CAP) {
        union { float f; int i; } nb; nb.f = norm[e];
        s_edge[(size_t)d * CAP + p] = make_int2(src[e] | (eid[e] << 20), nb.i);
      }
    }
  } else {
    int t = (bid - SCAT_B) * 256 + threadIdx.x;
    if (t < NN * 32) {                   // 4 h-elements per thread
      float4v v = *(const float4v*)(h + (size_t)t * 4);
      unsigned long long p = (unsigned long long)f2bf(v[0])
                           | ((unsigned long long)f2bf(v[1]) << 16)
                           | ((unsigned long long)f2bf(v[2]) << 32)
                           | ((unsigned long long)f2bf(v[3]) << 48);
      *(unsigned long long*)(hb + (size_t)t * 4) = p;
    } else {
      int u = t - NN * 32;
      if (u < FEAT * KC * 32) {
        int j = u & 7, g = u >> 3;
        int ln = g & 63, n0 = (g >> 6) & 7, c = g >> 9;
        int o = n0 * 16 + (ln & 15);
        int k = c * 32 + ((ln >> 4) << 3) + j;
        float v = (k < 640) ? weight[(k >> 7) * 16384 + (k & 127) * 128 + o]
                            : W0[(k - 640) * 128 + o];
        Bt[u] = f2bf(v);
      }
    }
  }
}

// 32-lane-per-node accumulate: lane holds 4 feats (one uint2 of bf16x4).
// r is uniform per 32-lane half -> 5-arm branch executes 1-2 arms; packed
// v_pk_fma_f32 via __builtin_elementwise_fma.
static __device__ __forceinline__ void accum_edge(float2v acc[RNUM][2], int ex,
                                                  int ey, uint2 v) {
  union { int i; float f; } nb; nb.i = ey;
  int r = ex >> 20;
  float2v nm2 = {nb.f, nb.f};
  union { unsigned u; float g; } a0, a1, a2, a3;
  a0.u = v.x << 16; a1.u = v.x & 0xFFFF0000u;
  a2.u = v.y << 16; a3.u = v.y & 0xFFFF0000u;
  float2v f01 = {a0.g, a1.g}, f23 = {a2.g, a3.g};
#define ACCR(R)                                                       \
  { acc[R][0] = __builtin_elementwise_fma(nm2, f01, acc[R][0]);       \
    acc[R][1] = __builtin_elementwise_fma(nm2, f23, acc[R][1]); }
  if (r == 0)      ACCR(0)
  else if (r == 1) ACCR(1)
  else if (r == 2) ACCR(2)
  else if (r == 3) ACCR(3)
  else             ACCR(4)
#undef ACCR
}

// ---- FUSED aggregate + GEMM -------------------------------------------------
// Block = 512 (8 waves), 32 nodes/block (3125 blocks; 32*3125 = 100000 exact).
// Phase 1: wave w owns nodes base+w*4..+3 processed as 2 sequential pairs;
//   within a pair, 32 lanes per node (g2 = lane>>5), lane t2 = lane&31 holds
//   feats t2*4..t2*4+3. uint2 gathers (256B/node-row). acc[5][2] float2v.
//   Results (5 rel chunks + identity) -> LDS via ds_write_b64 at the same
//   XOR-swizzled sidx as before (granule 16B split even/odd lane).
// Phase 2 (one barrier, unchanged): wave w computes out-cols n0 = w over both
//   16-row tiles; A-frags via swizzled ds_read_b128 (conflict-free); B-frags
//   from frag-linear Bt in L2 -- each granule read exactly once per block.
// Epilogue (unchanged): relu'd C via LDS fp32 [32][132] -> full-line stores.
__global__ __launch_bounds__(512, 6) void k_fused(
    const unsigned short* __restrict__ hb, const int* __restrict__ cnt,
    const int2* __restrict__ s_edge, const unsigned short* __restrict__ Bt,
    float* __restrict__ out) {
  __shared__ uint4 Atile[2 * KC * 64];   // 2 tiles x 24 chunks x 64 granules = 48KB
  int tid = threadIdx.x;
  int wv = tid >> 6, lane = tid & 63;
  int base = blockIdx.x * 32;
  uint4* Aw = Atile + (wv >> 2) * (KC * 64);
  uint2* Aw2 = (uint2*)Aw;
  const uint2* hb2 = (const uint2*)hb;

  // ---- phase 1: two node-pairs per wave; 32 lanes per node
  int g2 = lane >> 5, t2 = lane & 31;
  int cB = t2 >> 3, kk = (t2 >> 1) & 3, par = t2 & 1;
#pragma unroll 1
  for (int pp = 0; pp < 2; ++pp) {
    int node = base + wv * 4 + pp * 2 + g2;   // always < NN (exact division)
    int row = (wv & 3) * 4 + pp * 2 + g2;     // row within this wave's tile
    int glen = cnt[node]; if (glen > CAP) glen = CAP;
    const int4* ep4 = (const int4*)(s_edge + (size_t)node * CAP);
    uint2 idv = hb2[(size_t)node * 32 + t2];  // identity feats, off crit path
    float2v acc[RNUM][2] = {};
    int npair = glen >> 1;
    int4 d = (glen > 0) ? ep4[0] : make_int4(0, 0, 0, 0);
    for (int p = 0; p < npair; ++p) {
      int4 dn = ep4[p + 1];              // prefetch next pair (pad-safe)
      uint2 v0 = hb2[(d.x & 0xFFFFF) * 32 + t2];
      uint2 v1 = hb2[(d.z & 0xFFFFF) * 32 + t2];
      accum_edge(acc, d.x, d.y, v0);
      accum_edge(acc, d.z, d.w, v1);
      d = dn;
    }
    if (glen & 1) {                      // edge 2*npair is d.x of prefetched d
      uint2 v = hb2[(d.x & 0xFFFFF) * 32 + t2];
      accum_edge(acc, d.x, d.y, v);
    }
    // LDS writes (b64): granule sidx = c*64 + kk*16 + (row ^ ((c*4+kk)&7)),
    // even t2 -> bytes 0-7 (k0..k0+3), odd t2 -> bytes 8-15 (k0+4..k0+7).
#pragma unroll
    for (int rr = 0; rr < RNUM; ++rr) {
      int c = rr * 4 + cB;
      uint2 pk;
      pk.x = (unsigned)f2bf(acc[rr][0][0]) | ((unsigned)f2bf(acc[rr][0][1]) << 16);
      pk.y = (unsigned)f2bf(acc[rr][1][0]) | ((unsigned)f2bf(acc[rr][1][1]) << 16);
      int sidx = c * 64 + kk * 16 + (row ^ ((c * 4 + kk) & 7));
      Aw2[sidx * 2 + par] = pk;
    }
    {   // identity chunk: feats t2*4..t2*4+3 -> c = 20+cB
      int c = 20 + cB;
      int sidx = c * 64 + kk * 16 + (row ^ ((c * 4 + kk) & 7));
      Aw2[sidx * 2 + par] = idv;
    }
  }
  __syncthreads();

  // ---- phase 2: GEMM. Wave wv -> out-col tile n0 = wv, both row-tiles.
  int m = lane & 15, qq = lane >> 4;
  float4v cacc[2];
  cacc[0] = (float4v){0.f, 0.f, 0.f, 0.f};
  cacc[1] = (float4v){0.f, 0.f, 0.f, 0.f};
#pragma unroll
  for (int c = 0; c < KC; ++c) {
    int sx = qq * 16 + (m ^ ((c * 4 + qq) & 7));
    short8 af0 = *(const short8*)&Atile[c * 64 + sx];
    short8 af1 = *(const short8*)&Atile[KC * 64 + c * 64 + sx];
    short8 bf  = *(const short8*)&Bt[((c * 8 + wv) * 64 + lane) * 8];
    cacc[0] = __builtin_amdgcn_mfma_f32_16x16x32_bf16(af0, bf, cacc[0], 0, 0, 0);
    cacc[1] = __builtin_amdgcn_mfma_f32_16x16x32_bf16(af1, bf, cacc[1], 0, 0, 0);
  }

  // ---- epilogue: relu -> LDS fp32 [32][132] -> coalesced full-line stores
  __syncthreads();                        // all waves done reading Atile
  float* Cs = (float*)Atile;              // 32*132*4 = 16.9KB <= 48KB
#pragma unroll
  for (int tt = 0; tt < 2; ++tt)
#pragma unroll
    for (int r = 0; r < 4; ++r) {
      float v = cacc[tt][r];              // C/D layout: col=m, row=qq*4+r [m89]
      Cs[(tt * 16 + qq * 4 + r) * 132 + wv * 16 + m] = v > 0.f ? v : 0.f;
    }
  __syncthreads();
  int r0 = tid >> 4, c0 = (tid & 15) * 8; // wave writes 4 full 512B rows
  float4v w0 = *(const float4v*)&Cs[r0 * 132 + c0];
  float4v w1 = *(const float4v*)&Cs[r0 * 132 + c0 + 4];
  float* op = out + (size_t)(base + r0) * FEAT + c0;
  *(float4v*)op = w0;
  *(float4v*)(op + 4) = w1;
}

// ---- slow-but-correct fallback if ws_size is too small ----------------------
__global__ void k_slow_mm(const float* __restrict__ h, const float* __restrict__ W0,
                          float* __restrict__ out) {
  __shared__ float hn[128];
  int n = blockIdx.x, t = threadIdx.x;
  hn[t] = h[(size_t)n * 128 + t];
  __syncthreads();
  float a = 0.f;
  for (int i = 0; i < 128; ++i) a += hn[i] * W0[i * 128 + t];
  out[(size_t)n * 128 + t] = a;
}
__global__ void k_slow_edge(const float* __restrict__ h, const float* __restrict__ weight,
                            const float* __restrict__ norm, const int* __restrict__ src,
                            const int* __restrict__ dst, const int* __restrict__ eid,
                            float* __restrict__ out) {
  __shared__ float hs[128];
  int e = blockIdx.x, t = threadIdx.x;
  hs[t] = h[(size_t)src[e] * 128 + t];
  __syncthreads();
  const float* W = weight + (size_t)eid[e] * 16384;
  float a = 0.f;
  for (int i = 0; i < 128; ++i) a += hs[i] * W[i * 128 + t];
  atomicAdd(&out[(size_t)dst[e] * 128 + t], a * norm[e]);
}
__global__ void k_slow_relu(float* out) {
  int i = blockIdx.x * 256 + threadIdx.x;
  if (i < NN * FEAT) out[i] = fmaxf(out[i], 0.f);
}

extern "C" void kernel_launch(void* const* d_in, const int* in_sizes, int n_in,
                              void* d_out, int out_size, void* d_ws, size_t ws_size,
                              hipStream_t stream) {
  const float* h      = (const float*)d_in[0];
  const float* weight = (const float*)d_in[1];
  const float* W0     = (const float*)d_in[2];
  const float* norm   = (const float*)d_in[3];
  const int*   src    = (const int*)d_in[4];
  const int*   dst    = (const int*)d_in[5];
  const int*   eid    = (const int*)d_in[6];
  float* out = (float*)d_out;

  char* ws = (char*)d_ws;
  size_t off = 0;
  auto wsalloc = [&](size_t bytes) -> char* {
    char* p = ws + off;
    off += (bytes + 255) & ~(size_t)255;
    return p;
  };
  unsigned short* hb  = (unsigned short*)wsalloc((size_t)NN * FEAT * 2);  // 25.6 MB
  unsigned short* Bt  = (unsigned short*)wsalloc((size_t)FEAT * KC * 32 * 2);
  int*   cnt      = (int*)wsalloc((size_t)NN * 4);
  int2*  s_edge   = (int2*)wsalloc((size_t)NN * CAP * 8 + 256);           // 25.6 MB

  if (ws_size >= off) {
    hipMemsetAsync(cnt, 0, (size_t)NN * 4, stream);
    k_prep <<<SCAT_B + PREP_B, 256, 0, stream>>>(src, dst, eid, norm, h, weight,
                                                 W0, cnt, s_edge, hb, Bt);
    k_fused<<<NN / 32, 512, 0, stream>>>(hb, cnt, s_edge, Bt, out);
  } else {
    // workspace too small for the fast path: correct fallback
    k_slow_mm  <<<NN, 128, 0, stream>>>(h, W0, out);
    k_slow_edge<<<NE, 128, 0, stream>>>(h, weight, norm, src, dst, eid, out);
    k_slow_relu<<<(NN * FEAT + 255) / 256, 256, 0, stream>>>(out);
  }
}

// Round 9
// 236.605 us; speedup vs baseline: 1.1902x; 1.1902x over previous
//
#include <hip/hip_runtime.h>
#include <hip/hip_bf16.h>

// RGCN layer: out = relu(h@W0 + segment_sum(norm * h[src] @ W[rel], dst))
// R17 fused v10. Four dispatches: memset(cnt) -> k_prep -> k_scat -> k_fused.
// R8 post-mortem: v9's 5-arm branch spilled acc (WRITE 50->210MB, 150us).
// Root cause across v5/v9: ANY control-flow/ILP around the 5-bank acc array
// spills. Fix: remove the array. v10 sorts each node's 32-slot bucket by
// relation in prep (two-pass: k_prep counts per-(dst,rel) into packed 6-bit
// fields of cntA; k_scat places each edge at prefix(r)+pos, same bucket
// memory, +400KB cntB only). Phase 1 keeps v7's pair-loop/2-gather ILP but
// accumulates into a SINGLE 4-float acc (two float2v scalars, no masks),
// flushing to the rel's LDS chunk on rel change (sorted -> <=5 flushes,
// chunks pre-zeroed by same thread so skipped rels stay correct).
// Per-edge VALU ~34 -> ~12. Phase 2 / epilogue byte-identical to v7.
// Tripwires: WRITE >60MB = spill -> revert; fused flat = latency floor ->
// pivot (cooperative merge or roofline).

#define NN   100000
#define NE   600000
#define FEAT 128
#define RNUM 5
#define CAP  32    // bucket capacity per node; P(deg>=32)~1e-12 (proven)
#define KC   24    // k-chunks of 32 (5*128 rel + 128 identity = 768)

#define SCAT_B 2344            // ceil(NE/256)
#define PREP_T (NN * 32 + FEAT * KC * 32)
#define PREP_B ((PREP_T + 255) / 256)

typedef __attribute__((ext_vector_type(8))) short short8;
typedef __attribute__((ext_vector_type(4))) float float4v;
typedef __attribute__((ext_vector_type(2))) float float2v;

static __device__ __forceinline__ unsigned short f2bf(float x) {
  union { float f; unsigned u; } v; v.f = x;
  unsigned r = v.u + 0x7FFFu + ((v.u >> 16) & 1u);  // RNE
  return (unsigned short)(r >> 16);
}

// ---- pass A: per-(dst,rel) counts (packed 6-bit x5) + hb/Bt conversion ------
// Bt granule g = (c*8+n0)*64+ln (16B, j=0..7) holds B[k][o] for
// o = n0*16+(ln&15), k = c*32+((ln>>4)<<3)+j  (c = 0..23).
__global__ void k_prep(const int* __restrict__ dst, const int* __restrict__ eid,
                       const float* __restrict__ h, const float* __restrict__ weight,
                       const float* __restrict__ W0, int* __restrict__ cnt,
                       unsigned short* __restrict__ hb, unsigned short* __restrict__ Bt) {
  int bid = blockIdx.x;
  if (bid < SCAT_B) {
    int e = bid * 256 + threadIdx.x;
    if (e < NE) {
      int d = dst[e], r = eid[e];
      atomicAdd((unsigned*)&cnt[d], 1u << (6 * r));   // counts fit 6 bits
    }
  } else {
    int t = (bid - SCAT_B) * 256 + threadIdx.x;
    if (t < NN * 32) {                   // 4 h-elements per thread
      float4v v = *(const float4v*)(h + (size_t)t * 4);
      unsigned long long p = (unsigned long long)f2bf(v[0])
                           | ((unsigned long long)f2bf(v[1]) << 16)
                           | ((unsigned long long)f2bf(v[2]) << 32)
                           | ((unsigned long long)f2bf(v[3]) << 48);
      *(unsigned long long*)(hb + (size_t)t * 4) = p;
    } else {
      int u = t - NN * 32;
      if (u < FEAT * KC * 32) {
        int j = u & 7, g = u >> 3;
        int ln = g & 63, n0 = (g >> 6) & 7, c = g >> 9;
        int o = n0 * 16 + (ln & 15);
        int k = c * 32 + ((ln >> 4) << 3) + j;
        float v = (k < 640) ? weight[(k >> 7) * 16384 + (k & 127) * 128 + o]
                            : W0[(k - 640) * 128 + o];
        Bt[u] = f2bf(v);
      }
    }
  }
}

// ---- pass B: placed scatter -> rel-sorted 32-slot buckets -------------------
__global__ void k_scat(const int* __restrict__ src, const int* __restrict__ dst,
                       const int* __restrict__ eid, const float* __restrict__ norm,
                       int* __restrict__ cnt, int2* __restrict__ s_edge) {
  int e = blockIdx.x * 256 + threadIdx.x;
  if (e >= NE) return;
  int d = dst[e], r = eid[e];
  unsigned cw = *(const unsigned*)&cnt[d];            // final counts (pass A done)
  int c0 = cw & 63, c1 = (cw >> 6) & 63, c2 = (cw >> 12) & 63, c3 = (cw >> 18) & 63;
  int sr = (r > 0 ? c0 : 0) + (r > 1 ? c1 : 0) + (r > 2 ? c2 : 0) + (r > 3 ? c3 : 0);
  unsigned pos = atomicAdd((unsigned*)&cnt[NN + d], 1u << (6 * r));
  int p = (pos >> (6 * r)) & 63;
  int slot = sr + p;                                   // unique within bucket
  if (slot < CAP) {
    union { float f; int i; } nb; nb.f = norm[e];
    s_edge[(size_t)d * CAP + slot] = make_int2(src[e] | (r << 20), nb.i);
  }
}

// ---- FUSED aggregate + GEMM -------------------------------------------------
// Block = 512 (8 waves), 32 nodes/block (3125 blocks; 32*3125 = 100000 exact).
// Phase 1: wave w owns nodes base+w*4..+3 as 2 sequential pairs; 32 lanes per
//   node (lane t2 holds feats t2*4..t2*4+3, uint2 gathers, 256B/row). Bucket
//   is rel-sorted: single acc (a01,a23), flush to rel chunk on rel change;
//   chunks pre-zeroed by the same thread (same-thread LDS order guarantees).
//   v6 descriptor prefetch kept; 2 gathers in flight per pair.
// Phase 2 (one barrier, v7-identical): wave w -> out-col tile n0 = w over
//   both 16-row tiles; swizzled ds_read_b128 A-frags; Bt granule read once.
// Epilogue (v7-identical): relu'd C via LDS fp32 [32][132] -> 512B row stores.
__global__ __launch_bounds__(512, 6) void k_fused(
    const unsigned short* __restrict__ hb, const int* __restrict__ cnt,
    const int2* __restrict__ s_edge, const unsigned short* __restrict__ Bt,
    float* __restrict__ out) {
  __shared__ uint4 Atile[2 * KC * 64];   // 2 tiles x 24 chunks x 64 granules = 48KB
  int tid = threadIdx.x;
  int wv = tid >> 6, lane = tid & 63;
  int base = blockIdx.x * 32;
  uint4* Aw = Atile + (wv >> 2) * (KC * 64);
  uint2* Aw2 = (uint2*)Aw;
  const uint2* hb2 = (const uint2*)hb;

  // ---- phase 1: two node-pairs per wave; 32 lanes per node
  int g2 = lane >> 5, t2 = lane & 31;
  int cB = t2 >> 3, kk = (t2 >> 1) & 3, par = t2 & 1;
#pragma unroll 1
  for (int pp = 0; pp < 2; ++pp) {
    int node = base + wv * 4 + pp * 2 + g2;   // always < NN (exact division)
    int row = (wv & 3) * 4 + pp * 2 + g2;     // row within this wave's tile
    unsigned cw = *(const unsigned*)&cnt[node];
    int deg = (cw & 63) + ((cw >> 6) & 63) + ((cw >> 12) & 63) +
              ((cw >> 18) & 63) + ((cw >> 24) & 63);
    if (deg > CAP) deg = CAP;
    const int4* ep4 = (const int4*)(s_edge + (size_t)node * CAP);
    uint2 idv = hb2[(size_t)node * 32 + t2];  // identity feats, off crit path

    // pre-zero this node's 5 rel chunks (same thread overwrites on flush)
#pragma unroll
    for (int rr = 0; rr < RNUM; ++rr) {
      int c = rr * 4 + cB;
      Aw2[(c * 64 + kk * 16 + (row ^ ((c * 4 + kk) & 7))) * 2 + par] =
          make_uint2(0u, 0u);
    }
    {   // identity chunk: feats t2*4..t2*4+3 -> c = 20+cB
      int c = 20 + cB;
      Aw2[(c * 64 + kk * 16 + (row ^ ((c * 4 + kk) & 7))) * 2 + par] = idv;
    }

    float2v a01 = {0.f, 0.f}, a23 = {0.f, 0.f};
    int rcur = 0;
    auto flush = [&](int r) {
      uint2 pk;
      pk.x = (unsigned)f2bf(a01[0]) | ((unsigned)f2bf(a01[1]) << 16);
      pk.y = (unsigned)f2bf(a23[0]) | ((unsigned)f2bf(a23[1]) << 16);
      int c = r * 4 + cB;
      Aw2[(c * 64 + kk * 16 + (row ^ ((c * 4 + kk) & 7))) * 2 + par] = pk;
    };
    auto proc = [&](int ex, int ey, uint2 v) {
      int r = ex >> 20;
      if (r != rcur) {                    // sorted: rarely taken (<=4/node)
        flush(rcur);
        a01 = (float2v){0.f, 0.f}; a23 = (float2v){0.f, 0.f};
        rcur = r;
      }
      union { int i; float f; } nb; nb.i = ey;
      float2v nm2 = {nb.f, nb.f};
      union { unsigned u; float g; } u0, u1, u2, u3;
      u0.u = v.x << 16; u1.u = v.x & 0xFFFF0000u;
      u2.u = v.y << 16; u3.u = v.y & 0xFFFF0000u;
      float2v f01 = {u0.g, u1.g}, f23 = {u2.g, u3.g};
      a01 = __builtin_elementwise_fma(nm2, f01, a01);
      a23 = __builtin_elementwise_fma(nm2, f23, a23);
    };

    int npair = deg >> 1;
    int4 d = (deg > 0) ? ep4[0] : make_int4(0, 0, 0, 0);
    for (int p = 0; p < npair; ++p) {
      int4 dn = ep4[p + 1];              // prefetch next pair (pad-safe)
      uint2 v0 = hb2[(d.x & 0xFFFFF) * 32 + t2];
      uint2 v1 = hb2[(d.z & 0xFFFFF) * 32 + t2];
      proc(d.x, d.y, v0);
      proc(d.z, d.w, v1);
      d = dn;
    }
    if (deg & 1) {                       // edge 2*npair is d.x of prefetched d
      uint2 v = hb2[(d.x & 0xFFFFF) * 32 + t2];
      proc(d.x, d.y, v);
    }
    flush(rcur);                         // final segment (zeros ok if deg==0)
  }
  __syncthreads();

  // ---- phase 2: GEMM. Wave wv -> out-col tile n0 = wv, both row-tiles.
  int m = lane & 15, qq = lane >> 4;
  float4v cacc[2];
  cacc[0] = (float4v){0.f, 0.f, 0.f, 0.f};
  cacc[1] = (float4v){0.f, 0.f, 0.f, 0.f};
#pragma unroll
  for (int c = 0; c < KC; ++c) {
    int sx = qq * 16 + (m ^ ((c * 4 + qq) & 7));
    short8 af0 = *(const short8*)&Atile[c * 64 + sx];
    short8 af1 = *(const short8*)&Atile[KC * 64 + c * 64 + sx];
    short8 bf  = *(const short8*)&Bt[((c * 8 + wv) * 64 + lane) * 8];
    cacc[0] = __builtin_amdgcn_mfma_f32_16x16x32_bf16(af0, bf, cacc[0], 0, 0, 0);
    cacc[1] = __builtin_amdgcn_mfma_f32_16x16x32_bf16(af1, bf, cacc[1], 0, 0, 0);
  }

  // ---- epilogue: relu -> LDS fp32 [32][132] -> coalesced full-line stores
  __syncthreads();                        // all waves done reading Atile
  float* Cs = (float*)Atile;              // 32*132*4 = 16.9KB <= 48KB
#pragma unroll
  for (int tt = 0; tt < 2; ++tt)
#pragma unroll
    for (int r = 0; r < 4; ++r) {
      float v = cacc[tt][r];              // C/D layout: col=m, row=qq*4+r [m89]
      Cs[(tt * 16 + qq * 4 + r) * 132 + wv * 16 + m] = v > 0.f ? v : 0.f;
    }
  __syncthreads();
  int r0 = tid >> 4, c0 = (tid & 15) * 8; // wave writes 4 full 512B rows
  float4v w0 = *(const float4v*)&Cs[r0 * 132 + c0];
  float4v w1 = *(const float4v*)&Cs[r0 * 132 + c0 + 4];
  float* op = out + (size_t)(base + r0) * FEAT + c0;
  *(float4v*)op = w0;
  *(float4v*)(op + 4) = w1;
}

// ---- slow-but-correct fallback if ws_size is too small ----------------------
__global__ void k_slow_mm(const float* __restrict__ h, const float* __restrict__ W0,
                          float* __restrict__ out) {
  __shared__ float hn[128];
  int n = blockIdx.x, t = threadIdx.x;
  hn[t] = h[(size_t)n * 128 + t];
  __syncthreads();
  float a = 0.f;
  for (int i = 0; i < 128; ++i) a += hn[i] * W0[i * 128 + t];
  out[(size_t)n * 128 + t] = a;
}
__global__ void k_slow_edge(const float* __restrict__ h, const float* __restrict__ weight,
                            const float* __restrict__ norm, const int* __restrict__ src,
                            const int* __restrict__ dst, const int* __restrict__ eid,
                            float* __restrict__ out) {
  __shared__ float hs[128];
  int e = blockIdx.x, t = threadIdx.x;
  hs[t] = h[(size_t)src[e] * 128 + t];
  __syncthreads();
  const float* W = weight + (size_t)eid[e] * 16384;
  float a = 0.f;
  for (int i = 0; i < 128; ++i) a += hs[i] * W[i * 128 + t];
  atomicAdd(&out[(size_t)dst[e] * 128 + t], a * norm[e]);
}
__global__ void k_slow_relu(float* out) {
  int i = blockIdx.x * 256 + threadIdx.x;
  if (i < NN * FEAT) out[i] = fmaxf(out[i], 0.f);
}

extern "C" void kernel_launch(void* const* d_in, const int* in_sizes, int n_in,
                              void* d_out, int out_size, void* d_ws, size_t ws_size,
                              hipStream_t stream) {
  const float* h      = (const float*)d_in[0];
  const float* weight = (const float*)d_in[1];
  const float* W0     = (const float*)d_in[2];
  const float* norm   = (const float*)d_in[3];
  const int*   src    = (const int*)d_in[4];
  const int*   dst    = (const int*)d_in[5];
  const int*   eid    = (const int*)d_in[6];
  float* out = (float*)d_out;

  char* ws = (char*)d_ws;
  size_t off = 0;
  auto wsalloc = [&](size_t bytes) -> char* {
    char* p = ws + off;
    off += (bytes + 255) & ~(size_t)255;
    return p;
  };
  unsigned short* hb  = (unsigned short*)wsalloc((size_t)NN * FEAT * 2);  // 25.6 MB
  unsigned short* Bt  = (unsigned short*)wsalloc((size_t)FEAT * KC * 32 * 2);
  int*   cnt      = (int*)wsalloc((size_t)2 * NN * 4);                    // cntA+cntB
  int2*  s_edge   = (int2*)wsalloc((size_t)NN * CAP * 8 + 256);           // 25.6 MB

  if (ws_size >= off) {
    hipMemsetAsync(cnt, 0, (size_t)2 * NN * 4, stream);
    k_prep <<<SCAT_B + PREP_B, 256, 0, stream>>>(dst, eid, h, weight, W0,
                                                 cnt, hb, Bt);
    k_scat <<<SCAT_B, 256, 0, stream>>>(src, dst, eid, norm, cnt, s_edge);
    k_fused<<<NN / 32, 512, 0, stream>>>(hb, cnt, s_edge, Bt, out);
  } else {
    // workspace too small for the fast path: correct fallback
    k_slow_mm  <<<NN, 128, 0, stream>>>(h, W0, out);
    k_slow_edge<<<NE, 128, 0, stream>>>(h, weight, norm, src, dst, eid, out);
    k_slow_relu<<<(NN * FEAT + 255) / 256, 256, 0, stream>>>(out);
  }
}

// Round 10
// 203.809 us; speedup vs baseline: 1.3817x; 1.1609x over previous
//
#include <hip/hip_runtime.h>
#include <hip/hip_bf16.h>

// RGCN layer: out = relu(h@W0 + segment_sum(norm * h[src] @ W[rel], dst))
// R18 fused v11. Three dispatches: memset(cnt) -> k_prep -> k_fused.
// R9 post-mortem: v10 cut VALUBusy 53->38.7% with dur FLAT (70-71us) ->
// phase 1 is latency-floored; VALU/occupancy/ILP/sort all dead levers.
// k_scat's extra dispatch cost ~32us for ~3us work -> dispatch overhead is
// big. Non-fused remainder is a constant ~131-132us across all 3-dispatch
// variants; that's now the target.
// v11 = v7 (proven 204.3: unsorted buckets, masked acc, 40 VGPR no spill)
// minus the hb pass: k_fused gathers fp32 h DIRECTLY (float4/lane, 512B/row;
// gather is latency-bound so 2x bytes ~free), k_prep shrinks to scatter+Bt
// (grid 2344+384, ~77MB less traffic). fp32 accum also drops 4 unpack
// ops/edge. Identity row: load fp32, f2bf-pack in kernel.
// A/B read: total ~185-195 = k_prep work mattered; ~200+ = fixed dispatch
// overhead dominates -> R11 goes cooperative single-kernel.
// Tripwires: WRITE >60MB = spill -> revert; k_fused 70-76 expected.

#define NN   100000
#define NE   600000
#define FEAT 128
#define RNUM 5
#define CAP  32    // edge bucket capacity; P(deg>=32)~1e-12 per node (proven)
#define KC   24    // k-chunks of 32 (5*128 rel + 128 identity = 768)

#define SCAT_B 2344            // ceil(NE/256)
#define BT_B   384             // FEAT*KC*32/256 = 98304/256

typedef __attribute__((ext_vector_type(8))) short short8;
typedef __attribute__((ext_vector_type(4))) float float4v;

static __device__ __forceinline__ unsigned short f2bf(float x) {
  union { float f; unsigned u; } v; v.f = x;
  unsigned r = v.u + 0x7FFFu + ((v.u >> 16) & 1u);  // RNE
  return (unsigned short)(r >> 16);
}

// ---- edge->bucket scatter + frag-linear bf16 Bt build -----------------------
// Bt granule g = (c*8+n0)*64+ln (16B, j=0..7) holds B[k][o] for
// o = n0*16+(ln&15), k = c*32+((ln>>4)<<3)+j  (c = 0..23).
__global__ void k_prep(const int* __restrict__ src, const int* __restrict__ dst,
                       const int* __restrict__ eid, const float* __restrict__ norm,
                       const float* __restrict__ weight, const float* __restrict__ W0,
                       int* __restrict__ cnt, int2* __restrict__ s_edge,
                       unsigned short* __restrict__ Bt) {
  int bid = blockIdx.x;
  if (bid < SCAT_B) {
    int e = bid * 256 + threadIdx.x;
    if (e < NE) {
      int d = dst[e];
      int p = atomicAdd(&cnt[d], 1);
      if (p < CAP) {
        union { float f; int i; } nb; nb.f = norm[e];
        s_edge[(size_t)d * CAP + p] = make_int2(src[e] | (eid[e] << 20), nb.i);
      }
    }
  } else {
    int u = (bid - SCAT_B) * 256 + threadIdx.x;
    if (u < FEAT * KC * 32) {
      int j = u & 7, g = u >> 3;
      int ln = g & 63, n0 = (g >> 6) & 7, c = g >> 9;
      int o = n0 * 16 + (ln & 15);
      int k = c * 32 + ((ln >> 4) << 3) + j;
      float v = (k < 640) ? weight[(k >> 7) * 16384 + (k & 127) * 128 + o]
                          : W0[(k - 640) * 128 + o];
      Bt[u] = f2bf(v);
    }
  }
}

// 32-lane-per-node accumulate: lane holds 4 fp32 feats (one float4 gather).
static __device__ __forceinline__ void accum_edge(float acc[RNUM][4], int ex,
                                                  int ey, float4v v) {
  union { int i; float f; } nb; nb.i = ey;
  int r = ex >> 20;
  float nm[RNUM];
#pragma unroll
  for (int rr = 0; rr < RNUM; ++rr) nm[rr] = (r == rr) ? nb.f : 0.f;
#pragma unroll
  for (int rr = 0; rr < RNUM; ++rr)
#pragma unroll
    for (int i = 0; i < 4; ++i) acc[rr][i] += nm[rr] * v[i];
}

// ---- FUSED aggregate + GEMM -------------------------------------------------
// Block = 512 (8 waves), 32 nodes/block (3125 blocks; 32*3125 = 100000 exact).
// Phase 1: wave w owns nodes base+w*4..+3 as 2 sequential pairs; 32 lanes per
//   node (lane t2 holds feats t2*4..t2*4+3), float4 fp32 gathers straight
//   from h (512B/node-row, latency-bound so 2x bytes ~free). acc[5][4].
//   Results (5 rel chunks + f2bf-packed identity) -> LDS via ds_write_b64 at
//   the XOR-swizzled sidx (granule 16B split even/odd lane) [v7-proven].
// Phase 2 (one barrier, v7-identical): wave w -> out-col tile n0 = w over
//   both 16-row tiles; swizzled ds_read_b128 A-frags (conflict-free);
//   B-frags from frag-linear Bt in L2 -- each granule read once per block.
// Epilogue (v7-identical): relu'd C via LDS fp32 [32][132] -> 512B row stores.
__global__ __launch_bounds__(512, 6) void k_fused(
    const float* __restrict__ h, const int* __restrict__ cnt,
    const int2* __restrict__ s_edge, const unsigned short* __restrict__ Bt,
    float* __restrict__ out) {
  __shared__ uint4 Atile[2 * KC * 64];   // 2 tiles x 24 chunks x 64 granules = 48KB
  int tid = threadIdx.x;
  int wv = tid >> 6, lane = tid & 63;
  int base = blockIdx.x * 32;
  uint4* Aw = Atile + (wv >> 2) * (KC * 64);
  uint2* Aw2 = (uint2*)Aw;
  const float4v* hf4 = (const float4v*)h;

  // ---- phase 1: two node-pairs per wave; 32 lanes per node
  int g2 = lane >> 5, t2 = lane & 31;
  int cB = t2 >> 3, kk = (t2 >> 1) & 3, par = t2 & 1;
#pragma unroll 1
  for (int pp = 0; pp < 2; ++pp) {
    int node = base + wv * 4 + pp * 2 + g2;   // always < NN (exact division)
    int row = (wv & 3) * 4 + pp * 2 + g2;     // row within this wave's tile
    int glen = cnt[node]; if (glen > CAP) glen = CAP;
    const int4* ep4 = (const int4*)(s_edge + (size_t)node * CAP);
    float4v idf = hf4[(size_t)node * 32 + t2];  // identity feats (fp32)
    float acc[RNUM][4] = {};
    int npair = glen >> 1;
    int4 d = (glen > 0) ? ep4[0] : make_int4(0, 0, 0, 0);
    for (int p = 0; p < npair; ++p) {
      int4 dn = ep4[p + 1];              // prefetch next pair (pad-safe)
      float4v v0 = hf4[(size_t)(d.x & 0xFFFFF) * 32 + t2];
      float4v v1 = hf4[(size_t)(d.z & 0xFFFFF) * 32 + t2];
      accum_edge(acc, d.x, d.y, v0);
      accum_edge(acc, d.z, d.w, v1);
      d = dn;
    }
    if (glen & 1) {                      // edge 2*npair is d.x of prefetched d
      float4v v = hf4[(size_t)(d.x & 0xFFFFF) * 32 + t2];
      accum_edge(acc, d.x, d.y, v);
    }
    // LDS writes (b64): granule sidx = c*64 + kk*16 + (row ^ ((c*4+kk)&7)),
    // even t2 -> bytes 0-7 (k0..k0+3), odd t2 -> bytes 8-15 (k0+4..k0+7).
#pragma unroll
    for (int rr = 0; rr < RNUM; ++rr) {
      int c = rr * 4 + cB;
      uint2 pk;
      pk.x = (unsigned)f2bf(acc[rr][0]) | ((unsigned)f2bf(acc[rr][1]) << 16);
      pk.y = (unsigned)f2bf(acc[rr][2]) | ((unsigned)f2bf(acc[rr][3]) << 16);
      int sidx = c * 64 + kk * 16 + (row ^ ((c * 4 + kk) & 7));
      Aw2[sidx * 2 + par] = pk;
    }
    {   // identity chunk: feats t2*4..t2*4+3 (f2bf-packed) -> c = 20+cB
      int c = 20 + cB;
      uint2 idv;
      idv.x = (unsigned)f2bf(idf[0]) | ((unsigned)f2bf(idf[1]) << 16);
      idv.y = (unsigned)f2bf(idf[2]) | ((unsigned)f2bf(idf[3]) << 16);
      int sidx = c * 64 + kk * 16 + (row ^ ((c * 4 + kk) & 7));
      Aw2[sidx * 2 + par] = idv;
    }
  }
  __syncthreads();

  // ---- phase 2: GEMM. Wave wv -> out-col tile n0 = wv, both row-tiles.
  int m = lane & 15, qq = lane >> 4;
  float4v cacc[2];
  cacc[0] = (float4v){0.f, 0.f, 0.f, 0.f};
  cacc[1] = (float4v){0.f, 0.f, 0.f, 0.f};
#pragma unroll
  for (int c = 0; c < KC; ++c) {
    int sx = qq * 16 + (m ^ ((c * 4 + qq) & 7));
    short8 af0 = *(const short8*)&Atile[c * 64 + sx];
    short8 af1 = *(const short8*)&Atile[KC * 64 + c * 64 + sx];
    short8 bf  = *(const short8*)&Bt[((c * 8 + wv) * 64 + lane) * 8];
    cacc[0] = __builtin_amdgcn_mfma_f32_16x16x32_bf16(af0, bf, cacc[0], 0, 0, 0);
    cacc[1] = __builtin_amdgcn_mfma_f32_16x16x32_bf16(af1, bf, cacc[1], 0, 0, 0);
  }

  // ---- epilogue: relu -> LDS fp32 [32][132] -> coalesced full-line stores
  __syncthreads();                        // all waves done reading Atile
  float* Cs = (float*)Atile;              // 32*132*4 = 16.9KB <= 48KB
#pragma unroll
  for (int tt = 0; tt < 2; ++tt)
#pragma unroll
    for (int r = 0; r < 4; ++r) {
      float v = cacc[tt][r];              // C/D layout: col=m, row=qq*4+r [m89]
      Cs[(tt * 16 + qq * 4 + r) * 132 + wv * 16 + m] = v > 0.f ? v : 0.f;
    }
  __syncthreads();
  int r0 = tid >> 4, c0 = (tid & 15) * 8; // wave writes 4 full 512B rows
  float4v w0 = *(const float4v*)&Cs[r0 * 132 + c0];
  float4v w1 = *(const float4v*)&Cs[r0 * 132 + c0 + 4];
  float* op = out + (size_t)(base + r0) * FEAT + c0;
  *(float4v*)op = w0;
  *(float4v*)(op + 4) = w1;
}

// ---- slow-but-correct fallback if ws_size is too small ----------------------
__global__ void k_slow_mm(const float* __restrict__ h, const float* __restrict__ W0,
                          float* __restrict__ out) {
  __shared__ float hn[128];
  int n = blockIdx.x, t = threadIdx.x;
  hn[t] = h[(size_t)n * 128 + t];
  __syncthreads();
  float a = 0.f;
  for (int i = 0; i < 128; ++i) a += hn[i] * W0[i * 128 + t];
  out[(size_t)n * 128 + t] = a;
}
__global__ void k_slow_edge(const float* __restrict__ h, const float* __restrict__ weight,
                            const float* __restrict__ norm, const int* __restrict__ src,
                            const int* __restrict__ dst, const int* __restrict__ eid,
                            float* __restrict__ out) {
  __shared__ float hs[128];
  int e = blockIdx.x, t = threadIdx.x;
  hs[t] = h[(size_t)src[e] * 128 + t];
  __syncthreads();
  const float* W = weight + (size_t)eid[e] * 16384;
  float a = 0.f;
  for (int i = 0; i < 128; ++i) a += hs[i] * W[i * 128 + t];
  atomicAdd(&out[(size_t)dst[e] * 128 + t], a * norm[e]);
}
__global__ void k_slow_relu(float* out) {
  int i = blockIdx.x * 256 + threadIdx.x;
  if (i < NN * FEAT) out[i] = fmaxf(out[i], 0.f);
}

extern "C" void kernel_launch(void* const* d_in, const int* in_sizes, int n_in,
                              void* d_out, int out_size, void* d_ws, size_t ws_size,
                              hipStream_t stream) {
  const float* h      = (const float*)d_in[0];
  const float* weight = (const float*)d_in[1];
  const float* W0     = (const float*)d_in[2];
  const float* norm   = (const float*)d_in[3];
  const int*   src    = (const int*)d_in[4];
  const int*   dst    = (const int*)d_in[5];
  const int*   eid    = (const int*)d_in[6];
  float* out = (float*)d_out;

  char* ws = (char*)d_ws;
  size_t off = 0;
  auto wsalloc = [&](size_t bytes) -> char* {
    char* p = ws + off;
    off += (bytes + 255) & ~(size_t)255;
    return p;
  };
  unsigned short* Bt  = (unsigned short*)wsalloc((size_t)FEAT * KC * 32 * 2);
  int*   cnt      = (int*)wsalloc((size_t)NN * 4);
  int2*  s_edge   = (int2*)wsalloc((size_t)NN * CAP * 8 + 256);           // 25.6 MB

  if (ws_size >= off) {
    hipMemsetAsync(cnt, 0, (size_t)NN * 4, stream);
    k_prep <<<SCAT_B + BT_B, 256, 0, stream>>>(src, dst, eid, norm, weight,
                                               W0, cnt, s_edge, Bt);
    k_fused<<<NN / 32, 512, 0, stream>>>(h, cnt, s_edge, Bt, out);
  } else {
    // workspace too small for the fast path: correct fallback
    k_slow_mm  <<<NN, 128, 0, stream>>>(h, W0, out);
    k_slow_edge<<<NE, 128, 0, stream>>>(h, weight, norm, src, dst, eid, out);
    k_slow_relu<<<(NN * FEAT + 255) / 256, 256, 0, stream>>>(out);
  }
}